// Round 1
// baseline (2599.751 us; speedup 1.0000x reference)
//
#include <hip/hip_runtime.h>
#include <cstddef>

// Problem constants
static constexpr int B_    = 8;
static constexpr int CIN   = 16;
static constexpr int F_    = 1024;
static constexpr int T_    = 512;
static constexpr int D_    = 1024;
static constexpr int L_    = 4;
static constexpr int NT    = 512;    // N_TOKENS
static constexpr int M_    = T_ * B_;        // 4096 GEMM rows
static constexpr int K3    = 3 * D_;         // 3072

// ---------------------------------------------------------------------------
// Kernel 1: x[t][b][f] = relu( sum_c feats[b][c][f][t] * w[c] + bias )
// Block: 256 threads, tile 32(f) x 32(t), one b per blockIdx.z.
// Reads t-contiguous (coalesced), transposes through LDS, writes f-contiguous.
// ---------------------------------------------------------------------------
__global__ __launch_bounds__(256) void conv_relu_tr(
    const float* __restrict__ feats, const float* __restrict__ wv,
    const float* __restrict__ bv, float* __restrict__ x0) {
    __shared__ float tile[32][33];
    const int b  = blockIdx.z;
    const int f0 = blockIdx.y * 32;
    const int t0 = blockIdx.x * 32;
    const float bias = bv[0];

    const int tt = threadIdx.x & 31;   // t within tile
    const int fr = threadIdx.x >> 5;   // 0..7
    #pragma unroll
    for (int fo = 0; fo < 32; fo += 8) {
        const int f = fo + fr;
        float acc = bias;
        const float* p = feats + (((size_t)b * CIN) * F_ + (f0 + f)) * T_ + t0 + tt;
        #pragma unroll
        for (int c = 0; c < CIN; ++c) {
            acc += wv[c] * p[(size_t)c * F_ * T_];
        }
        tile[f][tt] = fmaxf(acc, 0.0f);
    }
    __syncthreads();
    const int ff = threadIdx.x & 31;
    const int tr = threadIdx.x >> 5;
    #pragma unroll
    for (int to = 0; to < 32; to += 8) {
        const int t = to + tr;
        x0[(size_t)(t0 + t) * (B_ * D_) + (size_t)b * D_ + f0 + ff] = tile[ff][t];
    }
}

// ---------------------------------------------------------------------------
// Kernel 2: fp32 tiled GEMM  C[M][N] = A[M][K] * Bm[K][N]
// 64x64 block tile, 256 threads, 4x4 per thread, K-chunk 16.
// REMAP_BIAS: epilogue adds bias[n] and remaps row (t*8+b) -> (b*512+t).
// ---------------------------------------------------------------------------
template <bool REMAP_BIAS>
__global__ __launch_bounds__(256) void gemm64(
    const float* __restrict__ A, const float* __restrict__ Bm,
    float* __restrict__ C, const float* __restrict__ bias,
    int N, int K) {
    __shared__ float As[16][68];
    __shared__ float Bs[16][64];

    const int tid = threadIdx.x;
    const int m0 = blockIdx.y * 64;
    const int n0 = blockIdx.x * 64;

    float acc[4][4] = {};

    const int ak = tid & 15;   // k for A loads
    const int am = tid >> 4;   // row group for A loads (16 rows/pass)
    const int bn = tid & 63;   // n for B loads
    const int bk = tid >> 6;   // k group for B loads (4 k/pass)
    const int ty = tid >> 4;   // 0..15 (m groups)
    const int tx = tid & 15;   // 0..15 (n groups)

    for (int k0 = 0; k0 < K; k0 += 16) {
        #pragma unroll
        for (int p = 0; p < 4; ++p) {
            As[ak][am + 16 * p] = A[(size_t)(m0 + am + 16 * p) * K + k0 + ak];
        }
        #pragma unroll
        for (int p = 0; p < 4; ++p) {
            Bs[bk + 4 * p][bn] = Bm[(size_t)(k0 + bk + 4 * p) * N + n0 + bn];
        }
        __syncthreads();
        #pragma unroll
        for (int k = 0; k < 16; ++k) {
            const float4 av = *(const float4*)&As[k][ty * 4];
            const float4 bvv = *(const float4*)&Bs[k][tx * 4];
            const float a4[4] = {av.x, av.y, av.z, av.w};
            const float b4[4] = {bvv.x, bvv.y, bvv.z, bvv.w};
            #pragma unroll
            for (int i = 0; i < 4; ++i)
                #pragma unroll
                for (int j = 0; j < 4; ++j)
                    acc[i][j] = fmaf(a4[i], b4[j], acc[i][j]);
        }
        __syncthreads();
    }

    #pragma unroll
    for (int i = 0; i < 4; ++i) {
        const int m = m0 + ty * 4 + i;
        #pragma unroll
        for (int j = 0; j < 4; ++j) {
            const int n = n0 + tx * 4 + j;
            if (!REMAP_BIAS) {
                C[(size_t)m * N + n] = acc[i][j];
            } else {
                const int bb = m & 7;       // row m = t*8 + b
                const int t  = m >> 3;
                C[((size_t)bb * T_ + t) * N + n] = acc[i][j] + bias[n];
            }
        }
    }
}

// ---------------------------------------------------------------------------
// Kernel 3: SRU recurrence + output gate. One thread per (b,d): independent
// scalar recurrence over t=0..511.
// U[t][b][k]: k in [0,1024)=x_tilde, [1024,2048)=f_pre, [2048,3072)=r_pre
// ---------------------------------------------------------------------------
__global__ __launch_bounds__(256) void sru_scan(
    const float* __restrict__ U, const float* __restrict__ x,
    const float* __restrict__ v, const float* __restrict__ bvec,
    float* __restrict__ h) {
    const int idx = blockIdx.x * blockDim.x + threadIdx.x;  // 0..8191
    const int d  = idx & (D_ - 1);
    const int bb = idx >> 10;

    const float vf = v[d];
    const float vr = v[D_ + d];
    const float bf = bvec[d];
    const float br = bvec[D_ + d];

    const float* u0 = U + (size_t)bb * K3 + d;
    const float* xp = x + idx;
    float*       hp = h + idx;

    float c = 0.0f;
    #pragma unroll 4
    for (int t = 0; t < T_; ++t) {
        const float* u = u0 + (size_t)t * (B_ * K3);
        const float xt = u[0];
        const float fp = u[D_];
        const float rp = u[2 * D_];
        const float xin = xp[(size_t)t * (B_ * D_)];

        const float f = 1.0f / (1.0f + __expf(-(fp + vf * c + bf)));
        c = f * c + (1.0f - f) * xt;
        const float r = 1.0f / (1.0f + __expf(-(rp + vr * c + br)));
        hp[(size_t)t * (B_ * D_)] = r * c + (1.0f - r) * xin;
    }
}

// ---------------------------------------------------------------------------
// Kernel 4: lengths // 2 as float
// ---------------------------------------------------------------------------
__global__ void lens_k(const int* __restrict__ lens, float* __restrict__ out) {
    const int i = threadIdx.x;
    if (i < B_) out[i] = (float)(lens[i] >> 1);
}

extern "C" void kernel_launch(void* const* d_in, const int* in_sizes, int n_in,
                              void* d_out, int out_size, void* d_ws, size_t ws_size,
                              hipStream_t stream) {
    const float* feats  = (const float*)d_in[0];
    const int*   lens   = (const int*)d_in[1];
    const float* conv_w = (const float*)d_in[2];
    const float* conv_b = (const float*)d_in[3];
    const float* sru_W  = (const float*)d_in[4];
    const float* sru_v  = (const float*)d_in[5];
    const float* sru_b  = (const float*)d_in[6];
    const float* fc_w   = (const float*)d_in[7];
    const float* fc_b   = (const float*)d_in[8];
    float* out = (float*)d_out;

    // workspace layout: xa (16.8MB) | xb (16.8MB) | U (50.3MB)
    float* xa = (float*)d_ws;
    float* xb = xa + (size_t)M_ * D_;
    float* U  = xb + (size_t)M_ * D_;

    // 1) conv + relu + transpose -> xa[t][b][f]
    dim3 gc(T_ / 32, F_ / 32, B_);
    conv_relu_tr<<<gc, 256, 0, stream>>>(feats, conv_w, conv_b, xa);

    // 2) SRU layers
    float* cur = xa;
    float* nxt = xb;
    for (int l = 0; l < L_; ++l) {
        dim3 g1(K3 / 64, M_ / 64);
        gemm64<false><<<g1, 256, 0, stream>>>(cur, sru_W + (size_t)l * D_ * K3, U,
                                              nullptr, K3, D_);
        sru_scan<<<(B_ * D_) / 256, 256, 0, stream>>>(
            U, cur, sru_v + (size_t)l * 2 * D_, sru_b + (size_t)l * 2 * D_, nxt);
        float* tmp = cur; cur = nxt; nxt = tmp;
    }

    // 3) FC: logits[b][t][k] (+bias, with (t*8+b)->(b*512+t) row remap)
    dim3 g2(NT / 64, M_ / 64);
    gemm64<true><<<g2, 256, 0, stream>>>(cur, fc_w, out, fc_b, NT, D_);

    // 4) lengths
    lens_k<<<1, 64, 0, stream>>>(lens, out + (size_t)M_ * NT);
}

// Round 2
// 892.338 us; speedup vs baseline: 2.9134x; 2.9134x over previous
//
#include <hip/hip_runtime.h>
#include <cstddef>
#include <cstdint>

// Problem constants
static constexpr int B_  = 8;
static constexpr int CIN = 16;
static constexpr int F_  = 1024;
static constexpr int T_  = 512;
static constexpr int D_  = 1024;
static constexpr int L_  = 4;
static constexpr int NT  = 512;         // N_TOKENS
static constexpr int M_  = T_ * B_;     // 4096 GEMM rows (m = t*8 + b)
static constexpr int K3  = 3 * D_;      // 3072

typedef __attribute__((ext_vector_type(8))) short short8;   // 8 bf16 in 4 VGPRs
typedef __attribute__((ext_vector_type(4))) float floatx4;  // MFMA accumulator

__device__ __forceinline__ unsigned short f2bf(float f) {
    unsigned int u = __builtin_bit_cast(unsigned int, f);
    u += 0x7FFFu + ((u >> 16) & 1u);    // round-to-nearest-even
    return (unsigned short)(u >> 16);
}
__device__ __forceinline__ float bf2f(unsigned short s) {
    unsigned int u = ((unsigned int)s) << 16;
    return __builtin_bit_cast(float, u);
}

// async 16B/lane global->LDS (lds base must be wave-uniform; HW scatters lane*16)
#define GLD16(g, l)                                                              \
    __builtin_amdgcn_global_load_lds(                                            \
        (__attribute__((address_space(1))) unsigned int*)(g),                    \
        (__attribute__((address_space(3))) unsigned int*)(l), 16, 0, 0)

// ---------------------------------------------------------------------------
// Kernel 1: x_bf16[t][b][f] = relu( sum_c feats[b][c][f][t]*w[c] + bias )
// 32x32 LDS transpose tile; reads t-contiguous, writes f-contiguous bf16.
// ---------------------------------------------------------------------------
__global__ __launch_bounds__(256) void conv_relu_tr(
    const float* __restrict__ feats, const float* __restrict__ wv,
    const float* __restrict__ bv, unsigned short* __restrict__ x0) {
    __shared__ float tile[32][33];
    const int b  = blockIdx.z;
    const int f0 = blockIdx.y * 32;
    const int t0 = blockIdx.x * 32;
    const float bias = bv[0];

    const int tt = threadIdx.x & 31;
    const int fr = threadIdx.x >> 5;   // 0..7
    #pragma unroll
    for (int fo = 0; fo < 32; fo += 8) {
        const int f = fo + fr;
        float acc = bias;
        const float* p = feats + (((size_t)b * CIN) * F_ + (f0 + f)) * T_ + t0 + tt;
        #pragma unroll
        for (int c = 0; c < CIN; ++c) acc += wv[c] * p[(size_t)c * F_ * T_];
        tile[f][tt] = fmaxf(acc, 0.0f);
    }
    __syncthreads();
    const int ff = threadIdx.x & 31;
    const int tr = threadIdx.x >> 5;
    #pragma unroll
    for (int to = 0; to < 32; to += 8) {
        const int t = to + tr;
        x0[(size_t)(t0 + t) * (B_ * D_) + (size_t)b * D_ + f0 + ff] = f2bf(tile[ff][t]);
    }
}

// ---------------------------------------------------------------------------
// Kernel 2: weight transpose + bf16 cast:  W[K][N] fp32  ->  Wt[N][K] bf16
// ---------------------------------------------------------------------------
__global__ __launch_bounds__(256) void transp_bf16(
    const float* __restrict__ W, unsigned short* __restrict__ Wt, int K, int N) {
    __shared__ float tile[32][33];
    const int k0 = blockIdx.y * 32;
    const int n0 = blockIdx.x * 32;
    const int x = threadIdx.x & 31;
    const int y = threadIdx.x >> 5;   // 0..7
    #pragma unroll
    for (int yo = 0; yo < 32; yo += 8)
        tile[yo + y][x] = W[(size_t)(k0 + yo + y) * N + n0 + x];
    __syncthreads();
    #pragma unroll
    for (int yo = 0; yo < 32; yo += 8)
        Wt[(size_t)(n0 + yo + y) * K + k0 + x] = f2bf(tile[x][yo + y]);
}

// ---------------------------------------------------------------------------
// Kernel 3: bf16 MFMA GEMM  C[M][N] (fp32) = A[M][K] * Bt[N][K]^T
// 128x128 block tile, BK=32, 256 threads (4 waves 2x2), 16x16x32 bf16 MFMA,
// global_load_lds width-16 staging (m97 structure).
// REMAP_BIAS: adds bias[n], remaps row (t*8+b) -> (b*512+t)*NT.
// ---------------------------------------------------------------------------
template <bool REMAP_BIAS>
__global__ __launch_bounds__(256) void gemm_mfma(
    const unsigned short* __restrict__ A,   // [M][K] bf16
    const unsigned short* __restrict__ Bt,  // [N][K] bf16
    float* __restrict__ C, const float* __restrict__ bias,
    int N, int K) {
    __shared__ unsigned short As[128 * 32];   // 8 KB, row-major [128][32]
    __shared__ unsigned short Bs[128 * 32];   // 8 KB

    const int tid  = threadIdx.x;
    const int lane = tid & 63;
    const int wid  = tid >> 6;
    const int m0 = blockIdx.y * 128;
    const int n0 = blockIdx.x * 128;
    const int wm = (wid >> 1) * 64;   // wave's 64x64 quadrant
    const int wn = (wid & 1) * 64;

    floatx4 acc[4][4];
    #pragma unroll
    for (int mi = 0; mi < 4; ++mi)
        #pragma unroll
        for (int ni = 0; ni < 4; ++ni)
            acc[mi][ni] = (floatx4){0.f, 0.f, 0.f, 0.f};

    // staging: pass p covers rows (tid>>2)+64p, byte-col (tid&3)*16
    const char* gA = (const char*)A;
    const char* gB = (const char*)Bt;
    const size_t rowstride = (size_t)K * 2;
    const size_t rA0 = (size_t)(m0 + (tid >> 2)) * rowstride + (tid & 3) * 16;
    const size_t rB0 = (size_t)(n0 + (tid >> 2)) * rowstride + (tid & 3) * 16;
    const size_t pstep = 64 * rowstride;   // +64 rows
    char* sA = (char*)As;
    char* sB = (char*)Bs;
    const int ldsbase = wid * 1024;        // wave-uniform

    const int rsel = lane & 15;
    const int koff = (lane >> 4) * 16;

    for (int k0 = 0; k0 < K; k0 += 32) {
        const size_t kb = (size_t)k0 * 2;
        GLD16(gA + rA0 + kb,         sA + ldsbase);
        GLD16(gA + rA0 + kb + pstep, sA + ldsbase + 4096);
        GLD16(gB + rB0 + kb,         sB + ldsbase);
        GLD16(gB + rB0 + kb + pstep, sB + ldsbase + 4096);
        __syncthreads();   // drains vmcnt -> staged data visible

        short8 af[4], bfv[4];
        #pragma unroll
        for (int mi = 0; mi < 4; ++mi)
            af[mi] = *(const short8*)(sA + ((wm + mi * 16 + rsel) * 64 + koff));
        #pragma unroll
        for (int ni = 0; ni < 4; ++ni)
            bfv[ni] = *(const short8*)(sB + ((wn + ni * 16 + rsel) * 64 + koff));
        #pragma unroll
        for (int mi = 0; mi < 4; ++mi)
            #pragma unroll
            for (int ni = 0; ni < 4; ++ni)
                acc[mi][ni] = __builtin_amdgcn_mfma_f32_16x16x32_bf16(
                    af[mi], bfv[ni], acc[mi][ni], 0, 0, 0);
        __syncthreads();   // protect LDS before next stage
    }

    // epilogue: C/D layout col=lane&15, row=(lane>>4)*4+i (verified m89/m91)
    const int cl = lane & 15;
    const int qr = lane >> 4;
    #pragma unroll
    for (int mi = 0; mi < 4; ++mi) {
        #pragma unroll
        for (int ni = 0; ni < 4; ++ni) {
            const int gn = n0 + wn + ni * 16 + cl;
            #pragma unroll
            for (int i = 0; i < 4; ++i) {
                const int gm = m0 + wm + mi * 16 + qr * 4 + i;
                if (!REMAP_BIAS) {
                    C[(size_t)gm * N + gn] = acc[mi][ni][i];
                } else {
                    const int t  = gm >> 3;
                    const int bb = gm & 7;
                    C[((size_t)bb * T_ + t) * NT + gn] = acc[mi][ni][i] + bias[gn];
                }
            }
        }
    }
}

// ---------------------------------------------------------------------------
// Kernel 4: SRU recurrence, one thread per (b,d). Software-pipelined unroll-8
// register double-buffer prefetch. x (bf16 in), h (bf16 out), U fp32.
// ---------------------------------------------------------------------------
__global__ __launch_bounds__(64) void sru_scan(
    const float* __restrict__ U, const unsigned short* __restrict__ x,
    const float* __restrict__ v, const float* __restrict__ bvec,
    unsigned short* __restrict__ h) {
    const int idx = blockIdx.x * 64 + threadIdx.x;  // 0..8191 = b*1024+d
    const int d  = idx & (D_ - 1);
    const int bb = idx >> 10;

    const float vf = v[d];
    const float vr = v[D_ + d];
    const float bf_ = bvec[d];
    const float br_ = bvec[D_ + d];

    const float* u0 = U + (size_t)bb * K3 + d;
    const unsigned short* xp = x + idx;
    unsigned short* hp = h + idx;

    constexpr int UNR = 8;
    constexpr int NB  = T_ / UNR;            // 64 batches
    constexpr size_t SU = (size_t)B_ * K3;   // U t-stride
    constexpr size_t SX = (size_t)B_ * D_;   // x/h t-stride

    float xt[2][UNR], fp[2][UNR], rp[2][UNR], xi[2][UNR];
    #pragma unroll
    for (int j = 0; j < UNR; ++j) {
        const float* u = u0 + (size_t)j * SU;
        xt[0][j] = u[0];
        fp[0][j] = u[D_];
        rp[0][j] = u[2 * D_];
        xi[0][j] = bf2f(xp[(size_t)j * SX]);
    }

    float c = 0.0f;
    #pragma unroll 2
    for (int bt = 0; bt < NB; ++bt) {
        const int cb = bt & 1;
        const int nb = cb ^ 1;
        if (bt + 1 < NB) {   // prefetch next batch while computing current
            #pragma unroll
            for (int j = 0; j < UNR; ++j) {
                const float* u = u0 + (size_t)((bt + 1) * UNR + j) * SU;
                xt[nb][j] = u[0];
                fp[nb][j] = u[D_];
                rp[nb][j] = u[2 * D_];
                xi[nb][j] = bf2f(xp[(size_t)((bt + 1) * UNR + j) * SX]);
            }
        }
        #pragma unroll
        for (int j = 0; j < UNR; ++j) {
            const float f = 1.0f / (1.0f + __expf(-(fp[cb][j] + vf * c + bf_)));
            c = f * c + (1.0f - f) * xt[cb][j];
            const float r = 1.0f / (1.0f + __expf(-(rp[cb][j] + vr * c + br_)));
            hp[(size_t)(bt * UNR + j) * SX] = f2bf(r * c + (1.0f - r) * xi[cb][j]);
        }
    }
}

// ---------------------------------------------------------------------------
// Kernel 5: lengths // 2 as float
// ---------------------------------------------------------------------------
__global__ void lens_k(const int* __restrict__ lens, float* __restrict__ out) {
    const int i = threadIdx.x;
    if (i < B_) out[i] = (float)(lens[i] >> 1);
}

extern "C" void kernel_launch(void* const* d_in, const int* in_sizes, int n_in,
                              void* d_out, int out_size, void* d_ws, size_t ws_size,
                              hipStream_t stream) {
    const float* feats  = (const float*)d_in[0];
    const int*   lens   = (const int*)d_in[1];
    const float* conv_w = (const float*)d_in[2];
    const float* conv_b = (const float*)d_in[3];
    const float* sru_W  = (const float*)d_in[4];
    const float* sru_v  = (const float*)d_in[5];
    const float* sru_b  = (const float*)d_in[6];
    const float* fc_w   = (const float*)d_in[7];
    const float* fc_b   = (const float*)d_in[8];
    float* out = (float*)d_out;

    // workspace: x0 bf16 (8.39MB) | x1 bf16 (8.39MB) | U fp32 (50.3MB) | Wt bf16 (6.3MB)
    unsigned short* x0 = (unsigned short*)d_ws;
    unsigned short* x1 = x0 + (size_t)M_ * D_;
    float* U = (float*)(x1 + (size_t)M_ * D_);
    unsigned short* Wt = (unsigned short*)(U + (size_t)M_ * K3);

    // 1) conv + relu + transpose -> x0[t][b][f] bf16
    dim3 gc(T_ / 32, F_ / 32, B_);
    conv_relu_tr<<<gc, 256, 0, stream>>>(feats, conv_w, conv_b, x0);

    // 2) SRU layers
    unsigned short* cur = x0;
    unsigned short* nxt = x1;
    for (int l = 0; l < L_; ++l) {
        transp_bf16<<<dim3(K3 / 32, D_ / 32), 256, 0, stream>>>(
            sru_W + (size_t)l * D_ * K3, Wt, D_, K3);
        gemm_mfma<false><<<dim3(K3 / 128, M_ / 128), 256, 0, stream>>>(
            cur, Wt, U, nullptr, K3, D_);
        sru_scan<<<(B_ * D_) / 64, 64, 0, stream>>>(
            U, cur, sru_v + (size_t)l * 2 * D_, sru_b + (size_t)l * 2 * D_, nxt);
        unsigned short* tmp = cur; cur = nxt; nxt = tmp;
    }

    // 3) FC: logits[b][t][k] with bias + row remap
    transp_bf16<<<dim3(NT / 32, D_ / 32), 256, 0, stream>>>(fc_w, Wt, D_, NT);
    gemm_mfma<true><<<dim3(NT / 128, M_ / 128), 256, 0, stream>>>(
        cur, Wt, out, fc_b, NT, D_);

    // 4) lengths
    lens_k<<<1, 64, 0, stream>>>(lens, out + (size_t)M_ * NT);
}

// Round 3
// 823.327 us; speedup vs baseline: 3.1576x; 1.0838x over previous
//
#include <hip/hip_runtime.h>
#include <cstddef>
#include <cstdint>

// Problem constants
static constexpr int B_  = 8;
static constexpr int CIN = 16;
static constexpr int F_  = 1024;
static constexpr int T_  = 512;
static constexpr int D_  = 1024;
static constexpr int L_  = 4;
static constexpr int NT  = 512;         // N_TOKENS
static constexpr int M_  = T_ * B_;     // 4096 GEMM rows (m = t*8 + b)
static constexpr int K3  = 3 * D_;      // 3072
static constexpr int NP  = 4 * D_;      // 4096 = padded gate-interleaved N

typedef __attribute__((ext_vector_type(8))) short short8;   // 8 bf16 in 4 VGPRs
typedef __attribute__((ext_vector_type(4))) float floatx4;  // MFMA accumulator

__device__ __forceinline__ unsigned short f2bf(float f) {
    unsigned int u = __builtin_bit_cast(unsigned int, f);
    u += 0x7FFFu + ((u >> 16) & 1u);    // round-to-nearest-even
    return (unsigned short)(u >> 16);
}
__device__ __forceinline__ float bf2f(unsigned short s) {
    unsigned int u = ((unsigned int)s) << 16;
    return __builtin_bit_cast(float, u);
}

// async 16B/lane global->LDS (lds base wave-uniform; HW scatters lane*16)
#define GLD16(g, l)                                                              \
    __builtin_amdgcn_global_load_lds(                                            \
        (__attribute__((address_space(1))) unsigned int*)(g),                    \
        (__attribute__((address_space(3))) unsigned int*)(l), 16, 0, 0)

// ---------------------------------------------------------------------------
// Kernel 1: x_bf16[t][b][f] = relu( sum_c feats[b][c][f][t]*w[c] + bias )
// 32(f) x 64(t) tile, float4 reads along t, LDS transpose, ushort4 writes.
// ---------------------------------------------------------------------------
__global__ __launch_bounds__(256) void conv_relu_tr(
    const float* __restrict__ feats, const float* __restrict__ wv,
    const float* __restrict__ bv, unsigned short* __restrict__ x0) {
    __shared__ float tile[32][68];      // [f][t], padded for float4 rows
    const int b  = blockIdx.z;
    const int f0 = blockIdx.y * 32;
    const int t0 = blockIdx.x * 64;
    const float bias = bv[0];

    const int t4 = threadIdx.x & 15;    // t-offset/4
    const int fi = threadIdx.x >> 4;    // 0..15
    #pragma unroll
    for (int fo = 0; fo < 32; fo += 16) {
        const int f = fo + fi;
        float4 acc = {bias, bias, bias, bias};
        const float* p = feats + (((size_t)b * CIN) * F_ + (f0 + f)) * T_ + t0 + t4 * 4;
        #pragma unroll
        for (int c = 0; c < CIN; ++c) {
            const float4 vv = *(const float4*)(p + (size_t)c * F_ * T_);
            const float w = wv[c];
            acc.x += w * vv.x; acc.y += w * vv.y;
            acc.z += w * vv.z; acc.w += w * vv.w;
        }
        acc.x = fmaxf(acc.x, 0.f); acc.y = fmaxf(acc.y, 0.f);
        acc.z = fmaxf(acc.z, 0.f); acc.w = fmaxf(acc.w, 0.f);
        *(float4*)&tile[f][t4 * 4] = acc;
    }
    __syncthreads();
    const int f4 = threadIdx.x & 7;     // f-offset/4
    const int tr = threadIdx.x >> 3;    // 0..31
    #pragma unroll
    for (int to = 0; to < 64; to += 32) {
        const int t = to + tr;
        unsigned short pk[4];
        #pragma unroll
        for (int q = 0; q < 4; ++q) pk[q] = f2bf(tile[f4 * 4 + q][t]);
        *(uint2*)&x0[(size_t)(t0 + t) * (B_ * D_) + (size_t)b * D_ + f0 + f4 * 4] =
            *(const uint2*)pk;
    }
}

// ---------------------------------------------------------------------------
// Kernel 2: weight prep (one launch, grid z = 0..16):
//  z<16: l=z>>2, j=z&3:  Wt[l][d*4+j][k] = bf16(sru_W[l][k][j*1024+d]), j==3 -> 0
//  z==16 (blockIdx.x<16): WtF[n][k] = bf16(fc_w[k][n])
// ---------------------------------------------------------------------------
__global__ __launch_bounds__(256) void prep_weights(
    const float* __restrict__ sru_W, const float* __restrict__ fc_w,
    unsigned short* __restrict__ Wt, unsigned short* __restrict__ WtF) {
    __shared__ float tile[32][33];
    const int z  = blockIdx.z;
    const int x  = threadIdx.x & 31;
    const int y8 = threadIdx.x >> 5;    // 0..7
    if (z < 16) {
        const int l = z >> 2, j = z & 3;
        const int d0 = blockIdx.x * 32;
        const int k0 = blockIdx.y * 32;
        unsigned short* Wo = Wt + (size_t)l * ((size_t)NP * D_);
        if (j < 3) {
            const float* W = sru_W + (size_t)l * D_ * K3;
            #pragma unroll
            for (int yo = 0; yo < 32; yo += 8)
                tile[yo + y8][x] = W[(size_t)(k0 + yo + y8) * K3 + j * D_ + d0 + x];
            __syncthreads();
            #pragma unroll
            for (int yo = 0; yo < 32; yo += 8) {
                const int dy = yo + y8;
                Wo[(size_t)((d0 + dy) * 4 + j) * D_ + k0 + x] = f2bf(tile[x][dy]);
            }
        } else {
            #pragma unroll
            for (int yo = 0; yo < 32; yo += 8)
                Wo[(size_t)((d0 + yo + y8) * 4 + 3) * D_ + k0 + x] = 0;
        }
    } else {
        if (blockIdx.x >= NT / 32) return;
        const int n0 = blockIdx.x * 32;
        const int k0 = blockIdx.y * 32;
        #pragma unroll
        for (int yo = 0; yo < 32; yo += 8)
            tile[yo + y8][x] = fc_w[(size_t)(k0 + yo + y8) * NT + n0 + x];
        __syncthreads();
        #pragma unroll
        for (int yo = 0; yo < 32; yo += 8)
            WtF[(size_t)(n0 + yo + y8) * D_ + k0 + x] = f2bf(tile[x][yo + y8]);
    }
}

// ---------------------------------------------------------------------------
// Kernel 3: bf16 MFMA GEMM  C[M][N] = A[M][K] * Bt[N][K]^T  (m97 structure)
// 128x128 tile, BK=32, 4 waves 2x2, 16x16x32 bf16 MFMA, global_load_lds w=16.
// MODE 0: C = bf16 (gate-interleaved U, plain row-major write)
// MODE 1: C = fp32, +bias[n], row remap (t*8+b) -> (b*512+t)
// ---------------------------------------------------------------------------
template <int MODE>
__global__ __launch_bounds__(256) void gemm_mfma(
    const unsigned short* __restrict__ A,   // [M][K] bf16
    const unsigned short* __restrict__ Bt,  // [N][K] bf16
    void* __restrict__ Cv, const float* __restrict__ bias,
    int N, int K) {
    __shared__ unsigned short As[128 * 32];
    __shared__ unsigned short Bs[128 * 32];

    const int tid  = threadIdx.x;
    const int lane = tid & 63;
    const int wid  = tid >> 6;
    const int m0 = blockIdx.y * 128;
    const int n0 = blockIdx.x * 128;
    const int wm = (wid >> 1) * 64;
    const int wn = (wid & 1) * 64;

    floatx4 acc[4][4];
    #pragma unroll
    for (int mi = 0; mi < 4; ++mi)
        #pragma unroll
        for (int ni = 0; ni < 4; ++ni)
            acc[mi][ni] = (floatx4){0.f, 0.f, 0.f, 0.f};

    const char* gA = (const char*)A;
    const char* gB = (const char*)Bt;
    const size_t rowstride = (size_t)K * 2;
    const size_t rA0 = (size_t)(m0 + (tid >> 2)) * rowstride + (tid & 3) * 16;
    const size_t rB0 = (size_t)(n0 + (tid >> 2)) * rowstride + (tid & 3) * 16;
    const size_t pstep = 64 * rowstride;
    char* sA = (char*)As;
    char* sB = (char*)Bs;
    const int ldsbase = wid * 1024;

    const int rsel = lane & 15;
    const int koff = (lane >> 4) * 16;   // byte offset of 8-bf16 k-group

    for (int k0 = 0; k0 < K; k0 += 32) {
        const size_t kb = (size_t)k0 * 2;
        GLD16(gA + rA0 + kb,         sA + ldsbase);
        GLD16(gA + rA0 + kb + pstep, sA + ldsbase + 4096);
        GLD16(gB + rB0 + kb,         sB + ldsbase);
        GLD16(gB + rB0 + kb + pstep, sB + ldsbase + 4096);
        __syncthreads();

        short8 af[4], bfv[4];
        #pragma unroll
        for (int mi = 0; mi < 4; ++mi)
            af[mi] = *(const short8*)(sA + ((wm + mi * 16 + rsel) * 64 + koff));
        #pragma unroll
        for (int ni = 0; ni < 4; ++ni)
            bfv[ni] = *(const short8*)(sB + ((wn + ni * 16 + rsel) * 64 + koff));
        #pragma unroll
        for (int mi = 0; mi < 4; ++mi)
            #pragma unroll
            for (int ni = 0; ni < 4; ++ni)
                acc[mi][ni] = __builtin_amdgcn_mfma_f32_16x16x32_bf16(
                    af[mi], bfv[ni], acc[mi][ni], 0, 0, 0);
        __syncthreads();
    }

    // C/D layout: col=lane&15, row=(lane>>4)*4+i  (verified m89/m91)
    const int cl = lane & 15;
    const int qr = lane >> 4;
    #pragma unroll
    for (int mi = 0; mi < 4; ++mi) {
        #pragma unroll
        for (int ni = 0; ni < 4; ++ni) {
            const int gn = n0 + wn + ni * 16 + cl;
            #pragma unroll
            for (int i = 0; i < 4; ++i) {
                const int gm = m0 + wm + mi * 16 + qr * 4 + i;
                if (MODE == 0) {
                    ((unsigned short*)Cv)[(size_t)gm * N + gn] = f2bf(acc[mi][ni][i]);
                } else {
                    const int t  = gm >> 3;
                    const int bb = gm & 7;
                    ((float*)Cv)[((size_t)bb * T_ + t) * NT + gn] =
                        acc[mi][ni][i] + bias[gn];
                }
            }
        }
    }
}

// ---------------------------------------------------------------------------
// Kernel 4: SRU recurrence. One thread per (b,d). U is gate-interleaved bf16
// [t*8+b][d*4+j] -> one uint2 load per t. Explicit 4-deep register pipeline
// (all buffer indices compile-time after unroll).
// ---------------------------------------------------------------------------
__global__ __launch_bounds__(64) void sru_scan(
    const unsigned short* __restrict__ U4, const unsigned short* __restrict__ x,
    const float* __restrict__ v, const float* __restrict__ bvec,
    unsigned short* __restrict__ h) {
    const int idx = blockIdx.x * 64 + threadIdx.x;  // b*1024 + d
    const int d  = idx & (D_ - 1);
    const int bb = idx >> 10;

    const float vf  = v[d];
    const float vr  = v[D_ + d];
    const float bf_ = bvec[d];
    const float br_ = bvec[D_ + d];

    const uint2* up = (const uint2*)U4 + (size_t)bb * D_ + d;  // per-t: +8192
    const unsigned short* xp = x + idx;                        // per-t: +8192
    unsigned short* hp = h + idx;

    constexpr int UNR  = 8;
    constexpr int PIPE = 4;
    constexpr int NB   = T_ / UNR;          // 64 stages
    constexpr size_t ST = (size_t)B_ * D_;  // 8192

    uint2 ub[PIPE][UNR];
    unsigned short xb[PIPE][UNR];
    #pragma unroll
    for (int p = 0; p < PIPE; ++p)
        #pragma unroll
        for (int j = 0; j < UNR; ++j) {
            const int t = p * UNR + j;
            ub[p][j] = up[(size_t)t * ST];
            xb[p][j] = xp[(size_t)t * ST];
        }

    float c = 0.0f;
    for (int bt = 0; bt < NB; bt += PIPE) {
        #pragma unroll
        for (int p = 0; p < PIPE; ++p) {
            const int s = bt + p;
            #pragma unroll
            for (int j = 0; j < UNR; ++j) {
                const uint2 u = ub[p][j];
                const float xt = bf2f((unsigned short)(u.x & 0xFFFFu));
                const float fp = bf2f((unsigned short)(u.x >> 16));
                const float rp = bf2f((unsigned short)(u.y & 0xFFFFu));
                const float xi = bf2f(xb[p][j]);
                const float e1 = __expf(-(fp + vf * c + bf_));
                const float f  = __builtin_amdgcn_rcpf(1.0f + e1);
                c = f * (c - xt) + xt;
                const float e2 = __expf(-(rp + vr * c + br_));
                const float r  = __builtin_amdgcn_rcpf(1.0f + e2);
                hp[(size_t)(s * UNR + j) * ST] = f2bf(r * (c - xi) + xi);
            }
            if (s + PIPE < NB) {
                #pragma unroll
                for (int j = 0; j < UNR; ++j) {
                    const int t = (s + PIPE) * UNR + j;
                    ub[p][j] = up[(size_t)t * ST];
                    xb[p][j] = xp[(size_t)t * ST];
                }
            }
        }
    }
}

// ---------------------------------------------------------------------------
// Kernel 5: lengths // 2 as float
// ---------------------------------------------------------------------------
__global__ void lens_k(const int* __restrict__ lens, float* __restrict__ out) {
    const int i = threadIdx.x;
    if (i < B_) out[i] = (float)(lens[i] >> 1);
}

extern "C" void kernel_launch(void* const* d_in, const int* in_sizes, int n_in,
                              void* d_out, int out_size, void* d_ws, size_t ws_size,
                              hipStream_t stream) {
    const float* feats  = (const float*)d_in[0];
    const int*   lens   = (const int*)d_in[1];
    const float* conv_w = (const float*)d_in[2];
    const float* conv_b = (const float*)d_in[3];
    const float* sru_W  = (const float*)d_in[4];
    const float* sru_v  = (const float*)d_in[5];
    const float* sru_b  = (const float*)d_in[6];
    const float* fc_w   = (const float*)d_in[7];
    const float* fc_b   = (const float*)d_in[8];
    float* out = (float*)d_out;

    // ws: x0 8.4MB | x1 8.4MB | U4 33.5MB | Wt 4x8.4MB | WtF 1MB  (~85MB)
    unsigned short* x0 = (unsigned short*)d_ws;
    unsigned short* x1 = x0 + (size_t)M_ * D_;
    unsigned short* U4 = x1 + (size_t)M_ * D_;
    unsigned short* Wt = U4 + (size_t)M_ * NP;
    unsigned short* WtF = Wt + (size_t)L_ * NP * D_;

    // 1) conv + relu + transpose -> x0[t][b][f] bf16
    conv_relu_tr<<<dim3(T_ / 64, F_ / 32, B_), 256, 0, stream>>>(
        feats, conv_w, conv_b, x0);

    // 2) all weight transposes in one launch
    prep_weights<<<dim3(32, 32, 17), 256, 0, stream>>>(sru_W, fc_w, Wt, WtF);

    // 3) SRU layers: GEMM (N=4096 gate-interleaved bf16) + scan
    unsigned short* cur = x0;
    unsigned short* nxt = x1;
    for (int l = 0; l < L_; ++l) {
        gemm_mfma<0><<<dim3(NP / 128, M_ / 128), 256, 0, stream>>>(
            cur, Wt + (size_t)l * NP * D_, U4, nullptr, NP, D_);
        sru_scan<<<(B_ * D_) / 64, 64, 0, stream>>>(
            U4, cur, sru_v + (size_t)l * 2 * D_, sru_b + (size_t)l * 2 * D_, nxt);
        unsigned short* tmp = cur; cur = nxt; nxt = tmp;
    }

    // 4) FC: logits[b][t][k] fp32 with bias + row remap
    gemm_mfma<1><<<dim3(NT / 128, M_ / 128), 256, 0, stream>>>(
        cur, WtF, out, fc_b, NT, D_);

    // 5) lengths
    lens_k<<<1, 64, 0, stream>>>(lens, out + (size_t)M_ * NT);
}

// Round 4
// 808.416 us; speedup vs baseline: 3.2159x; 1.0184x over previous
//
#include <hip/hip_runtime.h>
#include <cstddef>
#include <cstdint>

// Problem constants
static constexpr int B_  = 8;
static constexpr int CIN = 16;
static constexpr int F_  = 1024;
static constexpr int T_  = 512;
static constexpr int D_  = 1024;
static constexpr int L_  = 4;
static constexpr int NT  = 512;         // N_TOKENS
static constexpr int M_  = T_ * B_;     // 4096 GEMM rows (m = t*8 + b)
static constexpr int K3  = 3 * D_;      // 3072
static constexpr int NP  = 4 * D_;      // 4096 = padded gate-interleaved N

typedef __attribute__((ext_vector_type(8))) short short8;   // 8 bf16 in 4 VGPRs
typedef __attribute__((ext_vector_type(4))) float floatx4;  // MFMA accumulator

__device__ __forceinline__ unsigned short f2bf(float f) {
    unsigned int u = __builtin_bit_cast(unsigned int, f);
    u += 0x7FFFu + ((u >> 16) & 1u);    // round-to-nearest-even
    return (unsigned short)(u >> 16);
}
__device__ __forceinline__ float bf2f(unsigned short s) {
    unsigned int u = ((unsigned int)s) << 16;
    return __builtin_bit_cast(float, u);
}

// async 16B/lane global->LDS (lds base wave-uniform; HW scatters lane*16)
#define GLD16(g, l)                                                              \
    __builtin_amdgcn_global_load_lds(                                            \
        (__attribute__((address_space(1))) unsigned int*)(g),                    \
        (__attribute__((address_space(3))) unsigned int*)(l), 16, 0, 0)

// ---------------------------------------------------------------------------
// Kernel 1: x_bf16[t][b][f] = relu( sum_c feats[b][c][f][t]*w[c] + bias )
// 32(f) x 64(t) tile, float4 reads along t, LDS transpose, ushort4 writes.
// ---------------------------------------------------------------------------
__global__ __launch_bounds__(256) void conv_relu_tr(
    const float* __restrict__ feats, const float* __restrict__ wv,
    const float* __restrict__ bv, unsigned short* __restrict__ x0) {
    __shared__ float tile[32][68];      // [f][t], padded for float4 rows
    const int b  = blockIdx.z;
    const int f0 = blockIdx.y * 32;
    const int t0 = blockIdx.x * 64;
    const float bias = bv[0];

    const int t4 = threadIdx.x & 15;    // t-offset/4
    const int fi = threadIdx.x >> 4;    // 0..15
    #pragma unroll
    for (int fo = 0; fo < 32; fo += 16) {
        const int f = fo + fi;
        float4 acc = {bias, bias, bias, bias};
        const float* p = feats + (((size_t)b * CIN) * F_ + (f0 + f)) * T_ + t0 + t4 * 4;
        #pragma unroll
        for (int c = 0; c < CIN; ++c) {
            const float4 vv = *(const float4*)(p + (size_t)c * F_ * T_);
            const float w = wv[c];
            acc.x += w * vv.x; acc.y += w * vv.y;
            acc.z += w * vv.z; acc.w += w * vv.w;
        }
        acc.x = fmaxf(acc.x, 0.f); acc.y = fmaxf(acc.y, 0.f);
        acc.z = fmaxf(acc.z, 0.f); acc.w = fmaxf(acc.w, 0.f);
        *(float4*)&tile[f][t4 * 4] = acc;
    }
    __syncthreads();
    const int f4 = threadIdx.x & 7;     // f-offset/4
    const int tr = threadIdx.x >> 3;    // 0..31
    #pragma unroll
    for (int to = 0; to < 64; to += 32) {
        const int t = to + tr;
        unsigned short pk[4];
        #pragma unroll
        for (int q = 0; q < 4; ++q) pk[q] = f2bf(tile[f4 * 4 + q][t]);
        *(uint2*)&x0[(size_t)(t0 + t) * (B_ * D_) + (size_t)b * D_ + f0 + f4 * 4] =
            *(const uint2*)pk;
    }
}

// ---------------------------------------------------------------------------
// Kernel 2: weight prep (one launch, grid z = 0..16):
//  z<16: l=z>>2, j=z&3:  Wt[l][d*4+j][k] = bf16(sru_W[l][k][j*1024+d])
//        j==3 -> IDENTITY row e_d (routes x through the GEMM exactly)
//  z==16 (blockIdx.x<16): WtF[n][k] = bf16(fc_w[k][n])
// ---------------------------------------------------------------------------
__global__ __launch_bounds__(256) void prep_weights(
    const float* __restrict__ sru_W, const float* __restrict__ fc_w,
    unsigned short* __restrict__ Wt, unsigned short* __restrict__ WtF) {
    __shared__ float tile[32][33];
    const int z  = blockIdx.z;
    const int x  = threadIdx.x & 31;
    const int y8 = threadIdx.x >> 5;    // 0..7
    if (z < 16) {
        const int l = z >> 2, j = z & 3;
        const int d0 = blockIdx.x * 32;
        const int k0 = blockIdx.y * 32;
        unsigned short* Wo = Wt + (size_t)l * ((size_t)NP * D_);
        if (j < 3) {
            const float* W = sru_W + (size_t)l * D_ * K3;
            #pragma unroll
            for (int yo = 0; yo < 32; yo += 8)
                tile[yo + y8][x] = W[(size_t)(k0 + yo + y8) * K3 + j * D_ + d0 + x];
            __syncthreads();
            #pragma unroll
            for (int yo = 0; yo < 32; yo += 8) {
                const int dy = yo + y8;
                Wo[(size_t)((d0 + dy) * 4 + j) * D_ + k0 + x] = f2bf(tile[x][dy]);
            }
        } else {
            #pragma unroll
            for (int yo = 0; yo < 32; yo += 8) {
                const int dy = d0 + yo + y8;
                Wo[(size_t)(dy * 4 + 3) * D_ + k0 + x] =
                    (k0 + x == dy) ? (unsigned short)0x3F80u : (unsigned short)0u;
            }
        }
    } else {
        if (blockIdx.x >= NT / 32) return;
        const int n0 = blockIdx.x * 32;
        const int k0 = blockIdx.y * 32;
        #pragma unroll
        for (int yo = 0; yo < 32; yo += 8)
            tile[yo + y8][x] = fc_w[(size_t)(k0 + yo + y8) * NT + n0 + x];
        __syncthreads();
        #pragma unroll
        for (int yo = 0; yo < 32; yo += 8)
            WtF[(size_t)(n0 + yo + y8) * D_ + k0 + x] = f2bf(tile[x][yo + y8]);
    }
}

// ---------------------------------------------------------------------------
// Kernel 3: bf16 MFMA GEMM  C[M][N] = A[M][K] * Bt[N][K]^T  (m97 structure)
// 128x128 tile, BK=32, 4 waves 2x2, 16x16x32 bf16 MFMA, global_load_lds w=16.
// MODE 0: C = bf16 (gate-interleaved U incl. x-copy via identity rows)
// MODE 1: C = fp32, +bias[n], row remap (t*8+b) -> (b*512+t)
// ---------------------------------------------------------------------------
template <int MODE>
__global__ __launch_bounds__(256) void gemm_mfma(
    const unsigned short* __restrict__ A,   // [M][K] bf16
    const unsigned short* __restrict__ Bt,  // [N][K] bf16
    void* __restrict__ Cv, const float* __restrict__ bias,
    int N, int K) {
    __shared__ unsigned short As[128 * 32];
    __shared__ unsigned short Bs[128 * 32];

    const int tid  = threadIdx.x;
    const int lane = tid & 63;
    const int wid  = tid >> 6;
    const int m0 = blockIdx.y * 128;
    const int n0 = blockIdx.x * 128;
    const int wm = (wid >> 1) * 64;
    const int wn = (wid & 1) * 64;

    floatx4 acc[4][4];
    #pragma unroll
    for (int mi = 0; mi < 4; ++mi)
        #pragma unroll
        for (int ni = 0; ni < 4; ++ni)
            acc[mi][ni] = (floatx4){0.f, 0.f, 0.f, 0.f};

    const char* gA = (const char*)A;
    const char* gB = (const char*)Bt;
    const size_t rowstride = (size_t)K * 2;
    const size_t rA0 = (size_t)(m0 + (tid >> 2)) * rowstride + (tid & 3) * 16;
    const size_t rB0 = (size_t)(n0 + (tid >> 2)) * rowstride + (tid & 3) * 16;
    const size_t pstep = 64 * rowstride;
    char* sA = (char*)As;
    char* sB = (char*)Bs;
    const int ldsbase = wid * 1024;

    const int rsel = lane & 15;
    const int koff = (lane >> 4) * 16;   // byte offset of 8-bf16 k-group

    for (int k0 = 0; k0 < K; k0 += 32) {
        const size_t kb = (size_t)k0 * 2;
        GLD16(gA + rA0 + kb,         sA + ldsbase);
        GLD16(gA + rA0 + kb + pstep, sA + ldsbase + 4096);
        GLD16(gB + rB0 + kb,         sB + ldsbase);
        GLD16(gB + rB0 + kb + pstep, sB + ldsbase + 4096);
        __syncthreads();

        short8 af[4], bfv[4];
        #pragma unroll
        for (int mi = 0; mi < 4; ++mi)
            af[mi] = *(const short8*)(sA + ((wm + mi * 16 + rsel) * 64 + koff));
        #pragma unroll
        for (int ni = 0; ni < 4; ++ni)
            bfv[ni] = *(const short8*)(sB + ((wn + ni * 16 + rsel) * 64 + koff));
        #pragma unroll
        for (int mi = 0; mi < 4; ++mi)
            #pragma unroll
            for (int ni = 0; ni < 4; ++ni)
                acc[mi][ni] = __builtin_amdgcn_mfma_f32_16x16x32_bf16(
                    af[mi], bfv[ni], acc[mi][ni], 0, 0, 0);
        __syncthreads();
    }

    // C/D layout: col=lane&15, row=(lane>>4)*4+i  (verified m89/m91)
    const int cl = lane & 15;
    const int qr = lane >> 4;
    #pragma unroll
    for (int mi = 0; mi < 4; ++mi) {
        #pragma unroll
        for (int ni = 0; ni < 4; ++ni) {
            const int gn = n0 + wn + ni * 16 + cl;
            #pragma unroll
            for (int i = 0; i < 4; ++i) {
                const int gm = m0 + wm + mi * 16 + qr * 4 + i;
                if (MODE == 0) {
                    ((unsigned short*)Cv)[(size_t)gm * N + gn] = f2bf(acc[mi][ni][i]);
                } else {
                    const int t  = gm >> 3;
                    const int bb = gm & 7;
                    ((float*)Cv)[((size_t)bb * T_ + t) * NT + gn] =
                        acc[mi][ni][i] + bias[gn];
                }
            }
        }
    }
}

// ---------------------------------------------------------------------------
// Kernel 4: SRU recurrence. One thread per (b,d). U4[t*8+b][d*4+{0..3}] packs
// {x_tilde, f_pre, r_pre, x} -> ONE uint2 load per t. 4-deep register
// pipeline; 16 vm-ops/stage so the steady-state wait is vmcnt(48) <= 63.
// ---------------------------------------------------------------------------
__global__ __launch_bounds__(64) void sru_scan(
    const unsigned short* __restrict__ U4,
    const float* __restrict__ v, const float* __restrict__ bvec,
    unsigned short* __restrict__ h) {
    const int idx = blockIdx.x * 64 + threadIdx.x;  // b*1024 + d
    const int d  = idx & (D_ - 1);

    const float vfn = -v[d];
    const float vrn = -v[D_ + d];
    const float bf_ = bvec[d];
    const float br_ = bvec[D_ + d];

    const uint2* up = (const uint2*)U4 + idx;   // per-t stride: 8192 uint2
    unsigned short* hp = h + idx;               // per-t stride: 8192 ushort

    constexpr int UNR  = 8;
    constexpr int PIPE = 4;
    constexpr int NB   = T_ / UNR;          // 64 stages
    constexpr size_t ST = (size_t)B_ * D_;  // 8192

    uint2 ub[PIPE][UNR];
    #pragma unroll
    for (int p = 0; p < PIPE; ++p)
        #pragma unroll
        for (int j = 0; j < UNR; ++j)
            ub[p][j] = up[(size_t)(p * UNR + j) * ST];

    float c = 0.0f;
    for (int bt = 0; bt < NB; bt += PIPE) {
        #pragma unroll
        for (int p = 0; p < PIPE; ++p) {
            const int s = bt + p;
            #pragma unroll
            for (int j = 0; j < UNR; ++j) {
                const uint2 u = ub[p][j];
                const float xt  = bf2f((unsigned short)(u.x & 0xFFFFu));
                const float fpp = bf2f((unsigned short)(u.x >> 16));
                const float rpp = bf2f((unsigned short)(u.y & 0xFFFFu));
                const float xi  = bf2f((unsigned short)(u.y >> 16));
                // chain: fma -> exp -> add -> rcp -> fma (~28 cyc/t)
                const float e1 = __expf(fmaf(vfn, c, -(fpp + bf_)));
                const float f  = __builtin_amdgcn_rcpf(1.0f + e1);
                c = fmaf(f, c - xt, xt);
                const float e2 = __expf(fmaf(vrn, c, -(rpp + br_)));
                const float r  = __builtin_amdgcn_rcpf(1.0f + e2);
                hp[(size_t)(s * UNR + j) * ST] = f2bf(fmaf(r, c - xi, xi));
            }
            if (s + PIPE < NB) {
                #pragma unroll
                for (int j = 0; j < UNR; ++j)
                    ub[p][j] = up[(size_t)((s + PIPE) * UNR + j) * ST];
            }
        }
    }
}

// ---------------------------------------------------------------------------
// Kernel 5: lengths // 2 as float
// ---------------------------------------------------------------------------
__global__ void lens_k(const int* __restrict__ lens, float* __restrict__ out) {
    const int i = threadIdx.x;
    if (i < B_) out[i] = (float)(lens[i] >> 1);
}

extern "C" void kernel_launch(void* const* d_in, const int* in_sizes, int n_in,
                              void* d_out, int out_size, void* d_ws, size_t ws_size,
                              hipStream_t stream) {
    const float* feats  = (const float*)d_in[0];
    const int*   lens   = (const int*)d_in[1];
    const float* conv_w = (const float*)d_in[2];
    const float* conv_b = (const float*)d_in[3];
    const float* sru_W  = (const float*)d_in[4];
    const float* sru_v  = (const float*)d_in[5];
    const float* sru_b  = (const float*)d_in[6];
    const float* fc_w   = (const float*)d_in[7];
    const float* fc_b   = (const float*)d_in[8];
    float* out = (float*)d_out;

    // ws: x0 8.4MB | x1 8.4MB | U4 33.5MB | Wt 4x8.4MB | WtF 1MB  (~85MB)
    unsigned short* x0 = (unsigned short*)d_ws;
    unsigned short* x1 = x0 + (size_t)M_ * D_;
    unsigned short* U4 = x1 + (size_t)M_ * D_;
    unsigned short* Wt = U4 + (size_t)M_ * NP;
    unsigned short* WtF = Wt + (size_t)L_ * NP * D_;

    // 1) conv + relu + transpose -> x0[t][b][f] bf16
    conv_relu_tr<<<dim3(T_ / 64, F_ / 32, B_), 256, 0, stream>>>(
        feats, conv_w, conv_b, x0);

    // 2) all weight transposes in one launch (j=3 rows = identity)
    prep_weights<<<dim3(32, 32, 17), 256, 0, stream>>>(sru_W, fc_w, Wt, WtF);

    // 3) SRU layers: GEMM (N=4096 gate-interleaved bf16, x routed via
    //    identity block) + scan
    unsigned short* cur = x0;
    unsigned short* nxt = x1;
    for (int l = 0; l < L_; ++l) {
        gemm_mfma<0><<<dim3(NP / 128, M_ / 128), 256, 0, stream>>>(
            cur, Wt + (size_t)l * NP * D_, U4, nullptr, NP, D_);
        sru_scan<<<(B_ * D_) / 64, 64, 0, stream>>>(
            U4, sru_v + (size_t)l * 2 * D_, sru_b + (size_t)l * 2 * D_, nxt);
        unsigned short* tmp = cur; cur = nxt; nxt = tmp;
    }

    // 4) FC: logits[b][t][k] fp32 with bias + row remap
    gemm_mfma<1><<<dim3(NT / 128, M_ / 128), 256, 0, stream>>>(
        cur, WtF, out, fc_b, NT, D_);

    // 5) lengths
    lens_k<<<1, 64, 0, stream>>>(lens, out + (size_t)M_ * NT);
}